// Round 10
// baseline (113.389 us; speedup 1.0000x reference)
//
#include <hip/hip_runtime.h>
#include <cmath>

// SSIM loss, vertical-first row-sliding kernel, merged 3D+2D dispatch.
// Round-10: single-buffer 5-channel LDS row (10.5 KB; write|bar|read|bar),
// grid 2048 = 8 blocks/CU (hardware max: 32 waves/CU), depth-16 mean of img2
// inlined into the 2D path (no separate dispatch). launch_bounds(256,5) is
// the proven no-spill allocator setting (rounds 3/5/7/8: any tighter cap
// spills the f32x2 ring catastrophically).
// Block = 256 threads, each owns 2 adjacent columns; all math in f32x2
// ext-vectors (v_pk_*_f32). LDS stores vertical-blurred channels per
// column-PAIR: A4=(m1.x,m1.y,m2.x,m2.y) B4=(xx.x,xx.y,yy.x,yy.y) Z2=zz;
// horizontal taps = 7 slot reads at 16B lane stride (conflict-free) with
// compile-time packed coefficient pairs.

#define WSZ 11
#define IMG 512
#define SLICE (IMG * IMG)

typedef float f32x2 __attribute__((ext_vector_type(2)));
typedef float f32x4 __attribute__((ext_vector_type(4)));

struct G11 { float w[WSZ]; };

__global__ __launch_bounds__(256, 5)
void ssim_pk_kernel(const float* __restrict__ A3, const float* __restrict__ B3,
                    const float* __restrict__ A2,
                    double* __restrict__ acc, G11 gw)
{
    __shared__ f32x4 A4[262];   // (m1,m2) pairs, 3-slot pad each side
    __shared__ f32x4 B4[262];   // (xx,yy) pairs
    __shared__ f32x2 Z2[262];   // zz pairs
    __shared__ float bsum[4];

    const int tx = threadIdx.x;    // 0..255 = column pair index
    const int x0 = tx * 2;

    // decode work unit:
    //  [0,1792)    = 3D slice-bands: 64 slices x 28 bands (8x19 + 20x18 rows)
    //  [1792,2048) = 2D bands: 4 imgs x 64 bands of 8 rows, B = mean16(img2)
    const int unit = blockIdx.x;
    const bool m16 = (unit >= 1792);
    const float* Ap;
    const float* Bp;
    double* accp;
    int y0, TST;
    if (!m16) {
        int slice = unit / 28;
        int band  = unit - slice * 28;
        Ap = A3 + (long)slice * SLICE;
        Bp = B3 + (long)slice * SLICE;
        accp = acc + 0;
        if (band < 8) { y0 = band * 19;              TST = 19 + 10; }
        else          { y0 = 152 + (band - 8) * 18;  TST = 18 + 10; }
    } else {
        int uu = unit - 1792;
        int img  = uu >> 6;
        int band = uu & 63;
        Ap = A2 + (long)img * SLICE;
        Bp = B3 + (long)img * 16 * SLICE;   // img2[img, 0..15] for on-the-fly mean
        accp = acc + 1;
        y0 = band * 8;
        TST = 8 + 10;
    }

    // B-row loader: plain row for 3D, 16-slice mean for 2D (block-uniform path)
    auto loadB = [&](int r) -> f32x2 {
        if (!m16) return *(const f32x2*)&Bp[(long)r * IMG + x0];
        f32x2 s = {0.f, 0.f};
        #pragma unroll
        for (int d = 0; d < 16; d++)
            s += *(const f32x2*)&Bp[(long)d * SLICE + (long)r * IMG + x0];
        return s * 0.0625f;
    };

    // zero pads: pair slots 0..2 and 259..261
    if (tx < 3) {
        f32x4 z4 = {0.f, 0.f, 0.f, 0.f};
        f32x2 z2 = {0.f, 0.f};
        A4[tx] = z4; A4[259 + tx] = z4;
        B4[tx] = z4; B4[259 + tx] = z4;
        Z2[tx] = z2; Z2[259 + tx] = z2;
    }

    // 11-slot register ring of raw (a,b) pairs, statically indexed (unroll-11)
    f32x2 ra[11], rb[11];
    #pragma unroll
    for (int i = 0; i < 11; i++) { ra[i] = (f32x2){0.f, 0.f}; rb[i] = (f32x2){0.f, 0.f}; }

    float sum = 0.f;

    // prefetch first input row (r = y0 - 5)
    f32x2 aN = {0.f, 0.f}, bN = {0.f, 0.f};
    {
        int r = y0 - 5;
        if (r >= 0 && r < IMG) {
            aN = *(const f32x2*)&Ap[(long)r * IMG + x0];
            bN = loadB(r);
        }
    }

    const f32x2 C1v = {1e-4f, 1e-4f};
    const f32x2 C2v = {9e-4f, 9e-4f};

    for (int t0 = 0; t0 < TST; t0 += 11) {
        #pragma unroll
        for (int u = 0; u < 11; u++) {
            const int t = t0 + u;
            if (t < TST) {                    // block-uniform
                ra[u] = aN;
                rb[u] = bN;

                // prefetch next row (block-uniform guard)
                {
                    int rn = y0 - 4 + t;
                    aN = (f32x2){0.f, 0.f}; bN = (f32x2){0.f, 0.f};
                    if ((t + 1 < TST) && rn >= 0 && rn < IMG) {
                        aN = *(const f32x2*)&Ap[(long)rn * IMG + x0];
                        bN = loadB(rn);
                    }
                }

                if (t >= 10) {                // output row o = y0 + t - 10
                    // vertical 11-tap (packed): slot (u+1+j)%11 = row o-5+j
                    f32x2 m1 = {0.f, 0.f}, m2 = m1, xx = m1, yy = m1, zz = m1;
                    #pragma unroll
                    for (int j = 0; j < 11; j++) {
                        const int s = (u + 1 + j) % 11;     // compile-time
                        const f32x2 g2 = {gw.w[j], gw.w[j]};
                        f32x2 a = ra[s], b = rb[s];
                        f32x2 ga = g2 * a, gb = g2 * b;
                        m1 += ga; m2 += gb;
                        xx += ga * a; yy += gb * b; zz += ga * b;
                    }
                    A4[3 + tx] = __builtin_shufflevector(m1, m2, 0, 1, 2, 3);
                    B4[3 + tx] = __builtin_shufflevector(xx, yy, 0, 1, 2, 3);
                    Z2[3 + tx] = zz;
                    __syncthreads();          // writes visible before reads

                    // horizontal 11-tap over 7 pair slots, packed coefficients.
                    // slot jj holds cols (x0-6+2jj, x0-5+2jj); for output pair
                    // (x0, x0+1): e0 coeffs (g[2jj-1], g[2jj-2]), e1 (g[2jj], g[2jj-1]).
                    f32x2 OM1 = {0.f, 0.f}, OM2 = OM1, OXX = OM1, OYY = OM1, OZZ = OM1;
                    {   // jj = 0: only e1 with (g0, 0)
                        f32x4 pa = A4[tx], pb = B4[tx];
                        f32x2 pz = Z2[tx];
                        const f32x2 c = {gw.w[0], 0.f};
                        OM1 += c * __builtin_shufflevector(pa, pa, 1, 1);
                        OM2 += c * __builtin_shufflevector(pa, pa, 3, 3);
                        OXX += c * __builtin_shufflevector(pb, pb, 1, 1);
                        OYY += c * __builtin_shufflevector(pb, pb, 3, 3);
                        OZZ += c * __builtin_shufflevector(pz, pz, 1, 1);
                    }
                    #pragma unroll
                    for (int jj = 1; jj <= 5; jj++) {
                        f32x4 pa = A4[tx + jj], pb = B4[tx + jj];
                        f32x2 pz = Z2[tx + jj];
                        const f32x2 cA = {gw.w[2 * jj - 1], gw.w[2 * jj - 2]};
                        const f32x2 cB = {gw.w[2 * jj],     gw.w[2 * jj - 1]};
                        OM1 += cA * __builtin_shufflevector(pa, pa, 0, 0)
                             + cB * __builtin_shufflevector(pa, pa, 1, 1);
                        OM2 += cA * __builtin_shufflevector(pa, pa, 2, 2)
                             + cB * __builtin_shufflevector(pa, pa, 3, 3);
                        OXX += cA * __builtin_shufflevector(pb, pb, 0, 0)
                             + cB * __builtin_shufflevector(pb, pb, 1, 1);
                        OYY += cA * __builtin_shufflevector(pb, pb, 2, 2)
                             + cB * __builtin_shufflevector(pb, pb, 3, 3);
                        OZZ += cA * __builtin_shufflevector(pz, pz, 0, 0)
                             + cB * __builtin_shufflevector(pz, pz, 1, 1);
                    }
                    {   // jj = 6: only e0 with (0, g10)
                        f32x4 pa = A4[tx + 6], pb = B4[tx + 6];
                        f32x2 pz = Z2[tx + 6];
                        const f32x2 c = {0.f, gw.w[10]};
                        OM1 += c * __builtin_shufflevector(pa, pa, 0, 0);
                        OM2 += c * __builtin_shufflevector(pa, pa, 2, 2);
                        OXX += c * __builtin_shufflevector(pb, pb, 0, 0);
                        OYY += c * __builtin_shufflevector(pb, pb, 2, 2);
                        OZZ += c * __builtin_shufflevector(pz, pz, 0, 0);
                    }
                    __syncthreads();          // reads done before next row's writes

                    // SSIM formula, packed where possible
                    f32x2 m1s = OM1 * OM1, m2s = OM2 * OM2, m12 = OM1 * OM2;
                    f32x2 s1 = OXX - m1s, s2 = OYY - m2s, s12 = OZZ - m12;
                    f32x2 d1 = m1s + m2s + C1v;
                    f32x2 d2 = s1 + s2 + C2v;
                    f32x2 num = (2.f * m12 + C1v) * (2.f * s12 + C2v) * (s12 + C2v);
                    float d3x = __builtin_amdgcn_sqrtf(s1.x) * __builtin_amdgcn_sqrtf(s2.x) + 9e-4f;
                    float d3y = __builtin_amdgcn_sqrtf(s1.y) * __builtin_amdgcn_sqrtf(s2.y) + 9e-4f;
                    sum += num.x * __builtin_amdgcn_rcpf(d1.x * d2.x * d3x);
                    sum += num.y * __builtin_amdgcn_rcpf(d1.y * d2.y * d3y);
                }
            }
        }
    }

    // block reduction: wave shuffle -> LDS -> one atomic per block
    for (int off = 32; off > 0; off >>= 1)
        sum += __shfl_down(sum, off, 64);
    if ((tx & 63) == 0) bsum[tx >> 6] = sum;
    __syncthreads();
    if (tx == 0) {
        float tot = bsum[0] + bsum[1] + bsum[2] + bsum[3];
        atomicAdd(accp, (double)tot);
    }
}

__global__ void finalize_kernel(const double* __restrict__ acc, float* __restrict__ out)
{
    double loss3 = 1.0 - acc[0] / (64.0 * (double)SLICE);
    double loss2 = 1.0 - acc[1] / (4.0 * (double)SLICE);
    out[0] = (float)(loss3 + loss2);
}

extern "C" void kernel_launch(void* const* d_in, const int* in_sizes, int n_in,
                              void* d_out, int out_size, void* d_ws, size_t ws_size,
                              hipStream_t stream)
{
    const float* img1_3d = (const float*)d_in[0];   // [4,1,16,512,512] -> 64 slices
    const float* img1_2d = (const float*)d_in[1];   // [4,1,512,512]
    const float* img2    = (const float*)d_in[2];   // [4,1,16,512,512]
    float* out = (float*)d_out;

    double* acc = (double*)d_ws;                    // [0]=3D sum, [1]=2D sum

    // Gaussian weights, like cv2.getGaussianKernel(11, 1.5) in double.
    G11 gw;
    {
        double g[WSZ], s = 0.0;
        for (int i = 0; i < WSZ; i++) {
            double xx = (double)i - (WSZ - 1) / 2.0;
            g[i] = std::exp(-(xx * xx) / (2.0 * 1.5 * 1.5));
            s += g[i];
        }
        for (int i = 0; i < WSZ; i++) gw.w[i] = (float)(g[i] / s);
    }

    hipMemsetAsync(acc, 0, 2 * sizeof(double), stream);

    // merged SSIM: 1792 3D bands (64 x (8x19 + 20x18 rows)) + 256 2D bands
    // (4 imgs x 64x8 rows, mean16 inline) = 2048 blocks = 8 blocks/CU.
    ssim_pk_kernel<<<2048, 256, 0, stream>>>(img1_3d, img2, img1_2d, acc, gw);

    finalize_kernel<<<1, 1, 0, stream>>>(acc, out);
}